// Round 11
// baseline (457.624 us; speedup 1.0000x reference)
//
#include <hip/hip_runtime.h>
#include <hip/hip_bf16.h>
#include <stdint.h>

// MoE: T=4096 tokens, D_MODEL=1024, D_FF=4096, E=8, top-2.
// R11: 256x128 tiles (BM=256 halves weight re-staging; 792 vs 1056 MB staged
//      per GEMM), 4 waves each 128x64 out, 48 KiB LDS, drain core (r9),
//      split-K=2 gemm2 with bf16 partials, balanced XCD chunking.

#define T_TOK 4096
#define DM 1024
#define DF 4096
#define NE 8
#define BM 256              // M tile (pair rows)
#define BN 128              // N tile
#define BK 64               // K step
#define MAX_TILES 40        // sum ceil(c_e/256) <= 32 + 8
#define PAIR_CAP 10240      // MAX_TILES * 256

typedef __bf16 bf16x8 __attribute__((ext_vector_type(8)));
typedef float f32x4 __attribute__((ext_vector_type(4)));
typedef unsigned short ushort_t;

__device__ __forceinline__ ushort_t f2bf(float f) {
  uint32_t u = __float_as_uint(f);
  u += 0x7FFFu + ((u >> 16) & 1u);   // RNE
  return (ushort_t)(u >> 16);
}
__device__ __forceinline__ float bfl(uint32_t u) { return __uint_as_float(u << 16); }
__device__ __forceinline__ float bfh(uint32_t u) { return __uint_as_float(u & 0xFFFF0000u); }

// ---- workspace layout (bytes) ---- (r5-proven layout)
#define WT_OFF  0ull                 // [E][*][*] bf16 = 64MiB (w1t, then w2t)
#define XB_OFF  67108864ull          // [T][DM] bf16 = 8MiB
#define H_OFF   75497472ull          // [PAIR_CAP][DF] bf16 = 80MiB
#define PO_OFF  159383552ull         // [2][PAIR_CAP][DM] bf16 = 40MiB
#define RT_OFF  201326592ull         // routing block
#define RO_COUNTS   0
#define RO_OFFSETS  32
#define RO_CURSORS  64
#define RO_NTILES   96
#define RO_TILE_E   128
#define RO_TILE_S   320
#define RO_TILE_R   512
#define RO_PTOK     1024
#define RO_PW       41984
#define RO_TOPI     82944
#define RO_TOPW     115712
#define RO_PIDX     148480
#define RT_BYTES    181248ull
#define WS_NEEDED   (RT_OFF + RT_BYTES)

// Runtime-balanced XCD-chunked mapping (XCD of block b = b%8).
__device__ __forceinline__ int xcd_work(int b, int live) {
  int k = b & 7, j = b >> 3;
  int q = live >> 3, r = live & 7;
  int cnt = q + (k < r ? 1 : 0);
  if (j >= cnt) return -1;
  int start = k * q + (k < r ? k : r);
  return start + j;
}

// ------------------------------------------------------------------
// 1. Gating (+ fused x fp32 -> bf16)
// ------------------------------------------------------------------
__global__ void gate_kernel(const float* __restrict__ x, const float* __restrict__ gw,
                            int* __restrict__ counts, int* __restrict__ topi,
                            float* __restrict__ topw, ushort_t* __restrict__ xb) {
  int wave = threadIdx.x >> 6;
  int lane = threadIdx.x & 63;
  int t = blockIdx.x * 4 + wave;
  const float* xr = x + (size_t)t * DM;
  ushort_t* xbr = xb + (size_t)t * DM;
  float acc[NE];
#pragma unroll
  for (int e = 0; e < NE; ++e) acc[e] = 0.f;
  for (int d = lane; d < DM; d += 64) {
    float xv = xr[d];
    xbr[d] = f2bf(xv);
    const float* g = gw + (size_t)d * NE;
#pragma unroll
    for (int e = 0; e < NE; ++e) acc[e] += xv * g[e];
  }
#pragma unroll
  for (int off = 32; off > 0; off >>= 1) {
#pragma unroll
    for (int e = 0; e < NE; ++e) acc[e] += __shfl_xor(acc[e], off, 64);
  }
  if (lane == 0) {
    int i0 = 0; float v0 = acc[0];
#pragma unroll
    for (int e = 1; e < NE; ++e) if (acc[e] > v0) { v0 = acc[e]; i0 = e; }
    int i1 = -1; float v1 = -1e30f;
#pragma unroll
    for (int e = 0; e < NE; ++e) if (e != i0 && acc[e] > v1) { v1 = acc[e]; i1 = e; }
    float e1 = expf(v1 - v0);
    float w0 = 1.f / (1.f + e1);
    float w1 = e1 / (1.f + e1);
    topi[t * 2] = i0; topi[t * 2 + 1] = i1;
    topw[t * 2] = w0; topw[t * 2 + 1] = w1;
    atomicAdd(&counts[i0], 1);
    atomicAdd(&counts[i1], 1);
  }
}

// ------------------------------------------------------------------
// 2. Scan (BM=256 padding)
// ------------------------------------------------------------------
__global__ void scan_kernel(const int* __restrict__ counts, int* __restrict__ offsets,
                            int* __restrict__ cursors, int* __restrict__ n_tiles,
                            int* __restrict__ tile_e, int* __restrict__ tile_s,
                            int* __restrict__ tile_r) {
  if (threadIdx.x == 0) {
    int off = 0, nt = 0;
    for (int e = 0; e < NE; ++e) {
      offsets[e] = off;
      cursors[e] = 0;
      int c = counts[e];
      for (int m0 = 0; m0 < c; m0 += BM) {
        tile_e[nt] = e;
        tile_s[nt] = off + m0;
        tile_r[nt] = (c - m0 < BM) ? (c - m0) : BM;
        ++nt;
      }
      off += ((c + BM - 1) / BM) * BM;
    }
    *n_tiles = nt;
  }
}

// ------------------------------------------------------------------
// 3. Scatter (+ reverse map pidx)
// ------------------------------------------------------------------
__global__ void scatter_kernel(const int* __restrict__ topi, const float* __restrict__ topw,
                               const int* __restrict__ offsets, int* __restrict__ cursors,
                               int* __restrict__ ptok, float* __restrict__ pw,
                               int* __restrict__ pidx) {
  int t = blockIdx.x * 256 + threadIdx.x;
  if (t >= T_TOK) return;
#pragma unroll
  for (int k = 0; k < 2; ++k) {
    int e = topi[t * 2 + k];
    int pos = atomicAdd(&cursors[e], 1);
    int p = offsets[e] + pos;
    ptok[p] = t;
    pw[p] = topw[t * 2 + k];
    pidx[t * 2 + k] = p;
  }
}

// ------------------------------------------------------------------
// 4. weights: fp32 [E][R][C] -> bf16 transposed [E][C][R]
// ------------------------------------------------------------------
__global__ void transpose_convert(const float* __restrict__ src, ushort_t* __restrict__ dst,
                                  int R, int C) {
  __shared__ ushort_t tile[64][136];
  int e = blockIdx.z;
  src += (size_t)e * R * C;
  dst += (size_t)e * R * C;
  int c0 = blockIdx.x * 64, r0 = blockIdx.y * 128;
  int tr = threadIdx.x >> 4;
  int tc = (threadIdx.x & 15) << 2;
#pragma unroll
  for (int i = 0; i < 8; ++i) {
    int r = i * 16 + tr;
    float4 v = *(const float4*)&src[(size_t)(r0 + r) * C + c0 + tc];
    tile[tc + 0][r] = f2bf(v.x);
    tile[tc + 1][r] = f2bf(v.y);
    tile[tc + 2][r] = f2bf(v.z);
    tile[tc + 3][r] = f2bf(v.w);
  }
  __syncthreads();
  int cr = threadIdx.x >> 5;
  int rg = (threadIdx.x & 31) << 2;
#pragma unroll
  for (int j = 0; j < 8; ++j) {
    int c = j * 8 + cr;
    ushort4 o = { tile[c][rg], tile[c][rg + 1], tile[c][rg + 2], tile[c][rg + 3] };
    *(ushort4*)&dst[(size_t)(c0 + c) * R + r0 + rg] = o;
  }
}

// ==================================================================
// 256x128xBK64 grouped-GEMM core, 4 waves (2M x 2N), each 128x64 out.
// 48 KiB LDS (A 32 + B 16), single-buffered drain loop (r9-proven sync),
// LDS chunk^=(row&7) XOR swizzle (linear gload_lds dest + pre-swizzled
// global source + swizzled ds_read).
// ==================================================================

#define GLD(srcp, dstp)                                                        \
  __builtin_amdgcn_global_load_lds(                                            \
      (const __attribute__((address_space(1))) void*)(srcp),                   \
      (__attribute__((address_space(3))) void*)(dstp), 16, 0, 0)

__device__ __forceinline__ void gemm_core(
    ushort_t* As, ushort_t* Bs,
    const ushort_t* const (&a_sp)[8], const ushort_t* const (&b_sp)[4],
    int NT, int wid, int lane, f32x4 (&acc)[8][4]) {
  int fr = lane & 15, ch = lane >> 4, sw = lane & 7;
  int k0s = (ch ^ sw) * 8;            // kx0 swizzled chunk (ushort units)
  int k1s = ((ch + 4) ^ sw) * 8;      // kx1
  int wr = wid >> 1, wc = wid & 1;
  int abase = (wr * 128 + fr) * 64;
  int bbase = (wc * 64 + fr) * 64;

  for (int t = 0; t < NT; ++t) {
    int k0 = t * BK;
#pragma unroll
    for (int j = 0; j < 8; ++j) GLD(a_sp[j] + k0, As + (wid * 8 + j) * 512);
#pragma unroll
    for (int j = 0; j < 4; ++j) GLD(b_sp[j] + k0, Bs + (wid * 4 + j) * 512);
    asm volatile("s_waitcnt vmcnt(0)" ::: "memory");
    __syncthreads();

#pragma unroll
    for (int kx = 0; kx < 2; ++kx) {
      int ks = kx ? k1s : k0s;
      bf16x8 bf[4];
#pragma unroll
      for (int ni = 0; ni < 4; ++ni) bf[ni] = *(const bf16x8*)&Bs[bbase + ni * 1024 + ks];
#pragma unroll
      for (int mi = 0; mi < 8; ++mi) {
        bf16x8 af = *(const bf16x8*)&As[abase + mi * 1024 + ks];
#pragma unroll
        for (int ni = 0; ni < 4; ++ni)
          acc[mi][ni] = __builtin_amdgcn_mfma_f32_16x16x32_bf16(af, bf[ni], acc[mi][ni], 0, 0, 0);
      }
    }
    __syncthreads();
  }
}

// ------------------------------------------------------------------
// 5. GEMM1: h[p][:] = relu(x[tok(p)] @ W1_e)
// ------------------------------------------------------------------
__global__ __launch_bounds__(256, 2) void gemm1_kernel(
    const ushort_t* __restrict__ xb, const ushort_t* __restrict__ w1t,
    ushort_t* __restrict__ h,
    const int* __restrict__ n_tiles, const int* __restrict__ tile_e,
    const int* __restrict__ tile_s, const int* __restrict__ tile_r,
    const int* __restrict__ ptok) {
  int work = xcd_work(blockIdx.x, *n_tiles * (DF / BN));
  if (work < 0) return;
  int tile = work >> 5;               // DF/BN = 32
  int n0 = (work & 31) * BN;
  int e = tile_e[tile], p0 = tile_s[tile], rows = tile_r[tile];

  __shared__ ushort_t As[BM * BK];    // 32 KiB
  __shared__ ushort_t Bs[BN * BK];    // 16 KiB
  int tid = threadIdx.x, wid = tid >> 6, lane = tid & 63;
  int lr = lane >> 3;                      // 0..7 row within 8-row block
  int swc = (lane & 7) ^ (lr & 7);         // pre-swizzled k-chunk

  const ushort_t* a_sp[8];
  const ushort_t* b_sp[4];
#pragma unroll
  for (int j = 0; j < 8; ++j) {
    int r = wid * 64 + j * 8 + lr;         // 0..255
    int tok = (r < rows) ? ptok[p0 + r] : 0;
    a_sp[j] = xb + (size_t)tok * DM + swc * 8;
  }
#pragma unroll
  for (int j = 0; j < 4; ++j) {
    int r = wid * 32 + j * 8 + lr;         // 0..127
    b_sp[j] = w1t + ((size_t)e * DF + n0 + r) * DM + swc * 8;
  }

  f32x4 acc[8][4] = {};
  gemm_core(As, Bs, a_sp, b_sp, DM / BK, wid, lane, acc);

  // epilogue: relu -> bf16 h; pad rows written as zero (gemm2 reads them)
  int wr = wid >> 1, wc = wid & 1;
  int col = lane & 15, rq = (lane >> 4) * 4;
#pragma unroll
  for (int mi = 0; mi < 8; ++mi)
#pragma unroll
    for (int r = 0; r < 4; ++r) {
      int m = wr * 128 + mi * 16 + rq + r;
      bool valid = m < rows;
      size_t rowoff = (size_t)(p0 + m) * DF + n0 + wc * 64;
#pragma unroll
      for (int ni = 0; ni < 4; ++ni) {
        float v = acc[mi][ni][r];
        v = valid ? (v > 0.f ? v : 0.f) : 0.f;
        h[rowoff + ni * 16 + col] = f2bf(v);
      }
    }
}

// ------------------------------------------------------------------
// 6. GEMM2 (split-K=2): po[kh][p][:] = pw[p] * (h[p][kh] @ W2_e[kh])
// ------------------------------------------------------------------
__global__ __launch_bounds__(256, 2) void gemm2_kernel(
    const ushort_t* __restrict__ h, const ushort_t* __restrict__ w2t,
    ushort_t* __restrict__ po,
    const int* __restrict__ n_tiles, const int* __restrict__ tile_e,
    const int* __restrict__ tile_s, const int* __restrict__ tile_r,
    const float* __restrict__ pw) {
  int work = xcd_work(blockIdx.x, *n_tiles * (DM / BN) * 2);
  if (work < 0) return;
  int tile = work >> 4;               // 16 subs per tile (8 n0 x 2 kh)
  int sub = work & 15;
  int n0 = (sub >> 1) * BN;
  int kh = sub & 1;
  int kof = kh * (DF / 2);
  int e = tile_e[tile], p0 = tile_s[tile], rows = tile_r[tile];

  __shared__ ushort_t As[BM * BK];
  __shared__ ushort_t Bs[BN * BK];
  int tid = threadIdx.x, wid = tid >> 6, lane = tid & 63;
  int lr = lane >> 3;
  int swc = (lane & 7) ^ (lr & 7);

  const ushort_t* a_sp[8];
  const ushort_t* b_sp[4];
#pragma unroll
  for (int j = 0; j < 8; ++j) {
    int r = wid * 64 + j * 8 + lr;
    a_sp[j] = h + (size_t)(p0 + r) * DF + kof + swc * 8;   // pads zeroed by gemm1
  }
#pragma unroll
  for (int j = 0; j < 4; ++j) {
    int r = wid * 32 + j * 8 + lr;
    b_sp[j] = w2t + ((size_t)e * DM + n0 + r) * DF + kof + swc * 8;
  }

  f32x4 acc[8][4] = {};
  gemm_core(As, Bs, a_sp, b_sp, DF / (2 * BK), wid, lane, acc);

  ushort_t* pod = po + (size_t)kh * PAIR_CAP * DM;
  int wr = wid >> 1, wc = wid & 1;
  int col = lane & 15, rq = (lane >> 4) * 4;
#pragma unroll
  for (int mi = 0; mi < 8; ++mi)
#pragma unroll
    for (int r = 0; r < 4; ++r) {
      int m = wr * 128 + mi * 16 + rq + r;
      if (m < rows) {
        int p = p0 + m;
        float w = pw[p];
        size_t o = (size_t)p * DM + n0 + wc * 64;
#pragma unroll
        for (int ni = 0; ni < 4; ++ni)
          pod[o + ni * 16 + col] = f2bf(w * acc[mi][ni][r]);
      }
    }
}

// ------------------------------------------------------------------
// 7. Combine: out[t] = sum over {pa,pb} x {kh0,kh1} of bf16 po rows
// ------------------------------------------------------------------
__global__ void combine_kernel(const ushort_t* __restrict__ po, const int* __restrict__ pidx,
                               float* __restrict__ out) {
  int idx = blockIdx.x * 256 + threadIdx.x;   // T_TOK * DM/8 items
  int t = idx >> 7;                           // DM/8 = 128
  int d8 = (idx & 127) << 3;
  int pa = pidx[t * 2], pb = pidx[t * 2 + 1];
  const size_t HS = (size_t)PAIR_CAP * DM;
  size_t oa = (size_t)pa * DM + d8, ob = (size_t)pb * DM + d8;
  uint4 va0 = *(const uint4*)&po[oa];
  uint4 vb0 = *(const uint4*)&po[ob];
  uint4 va1 = *(const uint4*)&po[HS + oa];
  uint4 vb1 = *(const uint4*)&po[HS + ob];
  const uint32_t* A0 = (const uint32_t*)&va0;
  const uint32_t* B0 = (const uint32_t*)&vb0;
  const uint32_t* A1 = (const uint32_t*)&va1;
  const uint32_t* B1 = (const uint32_t*)&vb1;
  float r[8];
#pragma unroll
  for (int w = 0; w < 4; ++w) {
    r[2 * w]     = bfl(A0[w]) + bfl(B0[w]) + bfl(A1[w]) + bfl(B1[w]);
    r[2 * w + 1] = bfh(A0[w]) + bfh(B0[w]) + bfh(A1[w]) + bfh(B1[w]);
  }
  float4 o0 = { r[0], r[1], r[2], r[3] };
  float4 o1 = { r[4], r[5], r[6], r[7] };
  size_t ob2 = (size_t)t * DM + d8;
  *(float4*)&out[ob2] = o0;
  *(float4*)&out[ob2 + 4] = o1;
}

// ------------------------------------------------------------------
extern "C" void kernel_launch(void* const* d_in, const int* in_sizes, int n_in,
                              void* d_out, int out_size, void* d_ws, size_t ws_size,
                              hipStream_t stream) {
  const float* x  = (const float*)d_in[0];   // [2,2048,1024]
  const float* gw = (const float*)d_in[1];   // [1024,8]
  const float* w1 = (const float*)d_in[2];   // [8,1024,4096]
  const float* w2 = (const float*)d_in[3];   // [8,4096,1024]
  float* out = (float*)d_out;                // [4096,1024]
  char* ws = (char*)d_ws;
  if (ws_size < WS_NEEDED) return;

  ushort_t* wt  = (ushort_t*)(ws + WT_OFF);  // w1t, then w2t (region reuse)
  ushort_t* xb  = (ushort_t*)(ws + XB_OFF);
  ushort_t* h   = (ushort_t*)(ws + H_OFF);
  ushort_t* po  = (ushort_t*)(ws + PO_OFF);  // bf16 [2][PAIR_CAP][DM]
  char* rt = ws + RT_OFF;
  int*   counts  = (int*)(rt + RO_COUNTS);
  int*   offsets = (int*)(rt + RO_OFFSETS);
  int*   cursors = (int*)(rt + RO_CURSORS);
  int*   n_tiles = (int*)(rt + RO_NTILES);
  int*   tile_e  = (int*)(rt + RO_TILE_E);
  int*   tile_s  = (int*)(rt + RO_TILE_S);
  int*   tile_r  = (int*)(rt + RO_TILE_R);
  int*   ptok    = (int*)(rt + RO_PTOK);
  float* pw      = (float*)(rt + RO_PW);
  int*   topi    = (int*)(rt + RO_TOPI);
  float* topw    = (float*)(rt + RO_TOPW);
  int*   pidx    = (int*)(rt + RO_PIDX);

  hipMemsetAsync(rt, 0, 128, stream);

  hipLaunchKernelGGL(gate_kernel, dim3(T_TOK / 4), dim3(256), 0, stream,
                     x, gw, counts, topi, topw, xb);
  hipLaunchKernelGGL(scan_kernel, dim3(1), dim3(64), 0, stream,
                     counts, offsets, cursors, n_tiles, tile_e, tile_s, tile_r);
  hipLaunchKernelGGL(scatter_kernel, dim3(T_TOK / 256), dim3(256), 0, stream,
                     topi, topw, offsets, cursors, ptok, pw, pidx);
  hipLaunchKernelGGL(transpose_convert, dim3(DF / 64, DM / 128, NE), dim3(256), 0, stream,
                     w1, wt, DM, DF);                       // w1t into region A
  hipLaunchKernelGGL(gemm1_kernel, dim3(MAX_TILES * (DF / BN)), dim3(256), 0, stream,
                     xb, wt, h, n_tiles, tile_e, tile_s, tile_r, ptok);
  hipLaunchKernelGGL(transpose_convert, dim3(DM / 64, DF / 128, NE), dim3(256), 0, stream,
                     w2, wt, DF, DM);                       // w2t reuses region A
  hipLaunchKernelGGL(gemm2_kernel, dim3(MAX_TILES * (DM / BN) * 2), dim3(256), 0, stream,
                     h, wt, po, n_tiles, tile_e, tile_s, tile_r, pw);
  hipLaunchKernelGGL(combine_kernel, dim3((T_TOK * DM / 8) / 256), dim3(256), 0, stream,
                     po, pidx, out);
}

// Round 12
// 422.119 us; speedup vs baseline: 1.0841x; 1.0841x over previous
//
#include <hip/hip_runtime.h>
#include <hip/hip_bf16.h>
#include <stdint.h>

// MoE: T=4096 tokens, D_MODEL=1024, D_FF=4096, E=8, top-2.
// R12: r10 base (128x128 drain cores, proven 9.4 TB/s staging) with
//      gemm2 atomic epilogue (no split-K, no po, no combine) + vec gate.

#define T_TOK 4096
#define DM 1024
#define DF 4096
#define NE 8
#define BM 128              // M tile (pair rows)
#define BN 128              // N tile
#define BK 64               // K step
#define MAX_TILES 72        // sum ceil(c_e/128) <= 64 + 8
#define PAIR_CAP 9216       // MAX_TILES * 128

typedef __bf16 bf16x8 __attribute__((ext_vector_type(8)));
typedef float f32x4 __attribute__((ext_vector_type(4)));
typedef unsigned short ushort_t;

__device__ __forceinline__ ushort_t f2bf(float f) {
  uint32_t u = __float_as_uint(f);
  u += 0x7FFFu + ((u >> 16) & 1u);   // RNE
  return (ushort_t)(u >> 16);
}

// ---- workspace layout (bytes) ---- (r9/r10-proven, 72-tile spacing)
#define WT_OFF  0ull                 // [E][*][*] bf16 = 64MiB (w1t, then w2t)
#define XB_OFF  67108864ull          // [T][DM] bf16 = 8MiB
#define H_OFF   75497472ull          // [PAIR_CAP][DF] bf16 = 72MiB
#define RT_OFF  201326592ull         // routing block
#define RO_COUNTS   0
#define RO_OFFSETS  32
#define RO_CURSORS  64
#define RO_NTILES   96
#define RO_TILE_E   128              // 288B -> ends 416
#define RO_TILE_S   448              // 288B -> ends 736
#define RO_TILE_R   768              // 288B -> ends 1056
#define RO_PTOK     1088             // 36864B -> ends 37952
#define RO_PW       37952            // 36864B -> ends 74816
#define RO_TOPI     74816            // 32768B -> ends 107584
#define RO_TOPW     107584           // 32768B -> ends 140352
#define RT_BYTES    140352ull
#define WS_NEEDED   (RT_OFF + RT_BYTES)

// Runtime-balanced XCD-chunked mapping (XCD of block b = b%8).
__device__ __forceinline__ int xcd_work(int b, int live) {
  int k = b & 7, j = b >> 3;
  int q = live >> 3, r = live & 7;
  int cnt = q + (k < r ? 1 : 0);
  if (j >= cnt) return -1;
  int start = k * q + (k < r ? k : r);
  return start + j;
}

// ------------------------------------------------------------------
// 1. Gating (+ fused x fp32 -> bf16), float4-vectorized
// ------------------------------------------------------------------
__global__ void gate_kernel(const float* __restrict__ x, const float* __restrict__ gw,
                            int* __restrict__ counts, int* __restrict__ topi,
                            float* __restrict__ topw, ushort_t* __restrict__ xb) {
  int wave = threadIdx.x >> 6;
  int lane = threadIdx.x & 63;
  int t = blockIdx.x * 4 + wave;
  const float* xr = x + (size_t)t * DM;
  ushort_t* xbr = xb + (size_t)t * DM;
  float acc[NE];
#pragma unroll
  for (int e = 0; e < NE; ++e) acc[e] = 0.f;
#pragma unroll
  for (int it = 0; it < DM / 256; ++it) {
    int d0 = (it * 64 + lane) * 4;
    float4 v = *(const float4*)&xr[d0];
    ushort4 o = { f2bf(v.x), f2bf(v.y), f2bf(v.z), f2bf(v.w) };
    *(ushort4*)&xbr[d0] = o;
    const float* g0 = gw + (size_t)d0 * NE;
#pragma unroll
    for (int e = 0; e < NE; ++e)
      acc[e] += v.x * g0[e] + v.y * g0[NE + e] + v.z * g0[2 * NE + e] + v.w * g0[3 * NE + e];
  }
#pragma unroll
  for (int off = 32; off > 0; off >>= 1) {
#pragma unroll
    for (int e = 0; e < NE; ++e) acc[e] += __shfl_xor(acc[e], off, 64);
  }
  if (lane == 0) {
    int i0 = 0; float v0 = acc[0];
#pragma unroll
    for (int e = 1; e < NE; ++e) if (acc[e] > v0) { v0 = acc[e]; i0 = e; }
    int i1 = -1; float v1 = -1e30f;
#pragma unroll
    for (int e = 0; e < NE; ++e) if (e != i0 && acc[e] > v1) { v1 = acc[e]; i1 = e; }
    float e1 = expf(v1 - v0);
    float w0 = 1.f / (1.f + e1);
    float w1 = e1 / (1.f + e1);
    topi[t * 2] = i0; topi[t * 2 + 1] = i1;
    topw[t * 2] = w0; topw[t * 2 + 1] = w1;
    atomicAdd(&counts[i0], 1);
    atomicAdd(&counts[i1], 1);
  }
}

// ------------------------------------------------------------------
// 2. Scan (BM=128 padding)
// ------------------------------------------------------------------
__global__ void scan_kernel(const int* __restrict__ counts, int* __restrict__ offsets,
                            int* __restrict__ cursors, int* __restrict__ n_tiles,
                            int* __restrict__ tile_e, int* __restrict__ tile_s,
                            int* __restrict__ tile_r) {
  if (threadIdx.x == 0) {
    int off = 0, nt = 0;
    for (int e = 0; e < NE; ++e) {
      offsets[e] = off;
      cursors[e] = 0;
      int c = counts[e];
      for (int m0 = 0; m0 < c; m0 += BM) {
        tile_e[nt] = e;
        tile_s[nt] = off + m0;
        tile_r[nt] = (c - m0 < BM) ? (c - m0) : BM;
        ++nt;
      }
      off += ((c + BM - 1) / BM) * BM;
    }
    *n_tiles = nt;
  }
}

// ------------------------------------------------------------------
// 3. Scatter
// ------------------------------------------------------------------
__global__ void scatter_kernel(const int* __restrict__ topi, const float* __restrict__ topw,
                               const int* __restrict__ offsets, int* __restrict__ cursors,
                               int* __restrict__ ptok, float* __restrict__ pw) {
  int t = blockIdx.x * 256 + threadIdx.x;
  if (t >= T_TOK) return;
#pragma unroll
  for (int k = 0; k < 2; ++k) {
    int e = topi[t * 2 + k];
    int pos = atomicAdd(&cursors[e], 1);
    int p = offsets[e] + pos;
    ptok[p] = t;
    pw[p] = topw[t * 2 + k];
  }
}

// ------------------------------------------------------------------
// 4. weights: fp32 [E][R][C] -> bf16 transposed [E][C][R]
// ------------------------------------------------------------------
__global__ void transpose_convert(const float* __restrict__ src, ushort_t* __restrict__ dst,
                                  int R, int C) {
  __shared__ ushort_t tile[64][136];
  int e = blockIdx.z;
  src += (size_t)e * R * C;
  dst += (size_t)e * R * C;
  int c0 = blockIdx.x * 64, r0 = blockIdx.y * 128;
  int tr = threadIdx.x >> 4;
  int tc = (threadIdx.x & 15) << 2;
#pragma unroll
  for (int i = 0; i < 8; ++i) {
    int r = i * 16 + tr;
    float4 v = *(const float4*)&src[(size_t)(r0 + r) * C + c0 + tc];
    tile[tc + 0][r] = f2bf(v.x);
    tile[tc + 1][r] = f2bf(v.y);
    tile[tc + 2][r] = f2bf(v.z);
    tile[tc + 3][r] = f2bf(v.w);
  }
  __syncthreads();
  int cr = threadIdx.x >> 5;
  int rg = (threadIdx.x & 31) << 2;
#pragma unroll
  for (int j = 0; j < 8; ++j) {
    int c = j * 8 + cr;
    ushort4 o = { tile[c][rg], tile[c][rg + 1], tile[c][rg + 2], tile[c][rg + 3] };
    *(ushort4*)&dst[(size_t)(c0 + c) * R + r0 + rg] = o;
  }
}

// ==================================================================
// m97-replica 128x128xBK64 grouped-GEMM core, 4 waves (2M x 2N),
// 32 KiB single-buffered LDS, drain loop; multi-block/CU co-residency
// provides the latency hiding (m114). LDS chunk^=(row&7) XOR swizzle.
// ==================================================================

#define GLD(srcp, dstp)                                                        \
  __builtin_amdgcn_global_load_lds(                                            \
      (const __attribute__((address_space(1))) void*)(srcp),                   \
      (__attribute__((address_space(3))) void*)(dstp), 16, 0, 0)

__device__ __forceinline__ void gemm_core(
    ushort_t* As, ushort_t* Bs,
    const ushort_t* const (&a_sp)[4], const ushort_t* const (&b_sp)[4],
    int NT, int wid, int lane, f32x4 (&acc)[4][4]) {
  int fr = lane & 15, ch = lane >> 4, sw = lane & 7;
  int k0s = (ch ^ sw) * 8;            // kx0 swizzled chunk (ushort units)
  int k1s = ((ch + 4) ^ sw) * 8;      // kx1
  int m_off = (wid >> 1) * 64, n_off = (wid & 1) * 64;
  int abase = (m_off + fr) * 64;
  int bbase = (n_off + fr) * 64;

  for (int t = 0; t < NT; ++t) {
    int k0 = t * BK;
#pragma unroll
    for (int j = 0; j < 4; ++j) {
      GLD(a_sp[j] + k0, As + (wid * 4 + j) * 512);
      GLD(b_sp[j] + k0, Bs + (wid * 4 + j) * 512);
    }
    asm volatile("s_waitcnt vmcnt(0)" ::: "memory");
    __syncthreads();

#pragma unroll
    for (int kx = 0; kx < 2; ++kx) {
      int ks = kx ? k1s : k0s;
      bf16x8 af[4], bf[4];
#pragma unroll
      for (int mi = 0; mi < 4; ++mi) af[mi] = *(const bf16x8*)&As[abase + mi * 1024 + ks];
#pragma unroll
      for (int ni = 0; ni < 4; ++ni) bf[ni] = *(const bf16x8*)&Bs[bbase + ni * 1024 + ks];
#pragma unroll
      for (int mi = 0; mi < 4; ++mi)
#pragma unroll
        for (int ni = 0; ni < 4; ++ni)
          acc[mi][ni] = __builtin_amdgcn_mfma_f32_16x16x32_bf16(af[mi], bf[ni], acc[mi][ni], 0, 0, 0);
    }
    __syncthreads();
  }
}

// ------------------------------------------------------------------
// 5. GEMM1: h[p][:] = relu(x[tok(p)] @ W1_e)
// ------------------------------------------------------------------
__global__ __launch_bounds__(256, 4) void gemm1_kernel(
    const ushort_t* __restrict__ xb, const ushort_t* __restrict__ w1t,
    ushort_t* __restrict__ h,
    const int* __restrict__ n_tiles, const int* __restrict__ tile_e,
    const int* __restrict__ tile_s, const int* __restrict__ tile_r,
    const int* __restrict__ ptok) {
  int work = xcd_work(blockIdx.x, *n_tiles * (DF / BN));
  if (work < 0) return;
  int tile = work >> 5;               // DF/BN = 32
  int n0 = (work & 31) * BN;
  int e = tile_e[tile], p0 = tile_s[tile], rows = tile_r[tile];

  __shared__ ushort_t As[BM * BK];    // 16 KiB
  __shared__ ushort_t Bs[BN * BK];    // 16 KiB
  int tid = threadIdx.x, wid = tid >> 6, lane = tid & 63;
  int lr = lane >> 3;                      // 0..7 row within 8-row block
  int swc = (lane & 7) ^ (lr & 7);         // pre-swizzled k-chunk

  const ushort_t* a_sp[4];
  const ushort_t* b_sp[4];
#pragma unroll
  for (int j = 0; j < 4; ++j) {
    int r = wid * 32 + j * 8 + lr;         // 0..127
    int tok = (r < rows) ? ptok[p0 + r] : 0;
    a_sp[j] = xb + (size_t)tok * DM + swc * 8;
    b_sp[j] = w1t + ((size_t)e * DF + n0 + r) * DM + swc * 8;
  }

  f32x4 acc[4][4] = {};
  gemm_core(As, Bs, a_sp, b_sp, DM / BK, wid, lane, acc);

  // epilogue: relu -> bf16 h; pad rows written as zero (gemm2 reads them)
  int m_off = (wid >> 1) * 64, n_off = (wid & 1) * 64;
  int col = lane & 15, rq = (lane >> 4) * 4;
#pragma unroll
  for (int mi = 0; mi < 4; ++mi)
#pragma unroll
    for (int r = 0; r < 4; ++r) {
      int m = m_off + mi * 16 + rq + r;
      bool valid = m < rows;
      size_t rowoff = (size_t)(p0 + m) * DF + n0 + n_off;
#pragma unroll
      for (int ni = 0; ni < 4; ++ni) {
        float v = acc[mi][ni][r];
        v = valid ? (v > 0.f ? v : 0.f) : 0.f;
        h[rowoff + ni * 16 + col] = f2bf(v);
      }
    }
}

// ------------------------------------------------------------------
// 6. GEMM2: out[tok(p)] += pw[p] * (h[p] @ W2_e)   (atomic epilogue;
//    exactly 2 commutative fp32 adds per element -> deterministic)
// ------------------------------------------------------------------
__global__ __launch_bounds__(256, 4) void gemm2_kernel(
    const ushort_t* __restrict__ h, const ushort_t* __restrict__ w2t,
    float* __restrict__ out,
    const int* __restrict__ n_tiles, const int* __restrict__ tile_e,
    const int* __restrict__ tile_s, const int* __restrict__ tile_r,
    const int* __restrict__ ptok, const float* __restrict__ pw) {
  int work = xcd_work(blockIdx.x, *n_tiles * (DM / BN));
  if (work < 0) return;
  int tile = work >> 3;               // DM/BN = 8
  int n0 = (work & 7) * BN;
  int e = tile_e[tile], p0 = tile_s[tile], rows = tile_r[tile];

  __shared__ ushort_t As[BM * BK];
  __shared__ ushort_t Bs[BN * BK];
  int tid = threadIdx.x, wid = tid >> 6, lane = tid & 63;
  int lr = lane >> 3;
  int swc = (lane & 7) ^ (lr & 7);

  const ushort_t* a_sp[4];
  const ushort_t* b_sp[4];
#pragma unroll
  for (int j = 0; j < 4; ++j) {
    int r = wid * 32 + j * 8 + lr;
    a_sp[j] = h + (size_t)(p0 + r) * DF + swc * 8;        // pads zeroed by gemm1
    b_sp[j] = w2t + ((size_t)e * DM + n0 + r) * DF + swc * 8;
  }

  f32x4 acc[4][4] = {};
  gemm_core(As, Bs, a_sp, b_sp, DF / BK, wid, lane, acc);

  int m_off = (wid >> 1) * 64, n_off = (wid & 1) * 64;
  int col = lane & 15, rq = (lane >> 4) * 4;
#pragma unroll
  for (int mi = 0; mi < 4; ++mi)
#pragma unroll
    for (int r = 0; r < 4; ++r) {
      int m = m_off + mi * 16 + rq + r;
      if (m < rows) {
        int p = p0 + m;
        int tok = ptok[p];
        float w = pw[p];
        size_t o = (size_t)tok * DM + n0 + n_off;
#pragma unroll
        for (int ni = 0; ni < 4; ++ni)
          atomicAdd(&out[o + ni * 16 + col], w * acc[mi][ni][r]);
      }
    }
}

// ------------------------------------------------------------------
extern "C" void kernel_launch(void* const* d_in, const int* in_sizes, int n_in,
                              void* d_out, int out_size, void* d_ws, size_t ws_size,
                              hipStream_t stream) {
  const float* x  = (const float*)d_in[0];   // [2,2048,1024]
  const float* gw = (const float*)d_in[1];   // [1024,8]
  const float* w1 = (const float*)d_in[2];   // [8,1024,4096]
  const float* w2 = (const float*)d_in[3];   // [8,4096,1024]
  float* out = (float*)d_out;                // [4096,1024]
  char* ws = (char*)d_ws;
  if (ws_size < WS_NEEDED) return;

  ushort_t* wt  = (ushort_t*)(ws + WT_OFF);  // w1t, then w2t (region reuse)
  ushort_t* xb  = (ushort_t*)(ws + XB_OFF);
  ushort_t* h   = (ushort_t*)(ws + H_OFF);
  char* rt = ws + RT_OFF;
  int*   counts  = (int*)(rt + RO_COUNTS);
  int*   offsets = (int*)(rt + RO_OFFSETS);
  int*   cursors = (int*)(rt + RO_CURSORS);
  int*   n_tiles = (int*)(rt + RO_NTILES);
  int*   tile_e  = (int*)(rt + RO_TILE_E);
  int*   tile_s  = (int*)(rt + RO_TILE_S);
  int*   tile_r  = (int*)(rt + RO_TILE_R);
  int*   ptok    = (int*)(rt + RO_PTOK);
  float* pw      = (float*)(rt + RO_PW);
  int*   topi    = (int*)(rt + RO_TOPI);
  float* topw    = (float*)(rt + RO_TOPW);

  hipMemsetAsync(rt, 0, 128, stream);
  hipMemsetAsync(out, 0, (size_t)T_TOK * DM * sizeof(float), stream);

  hipLaunchKernelGGL(gate_kernel, dim3(T_TOK / 4), dim3(256), 0, stream,
                     x, gw, counts, topi, topw, xb);
  hipLaunchKernelGGL(scan_kernel, dim3(1), dim3(64), 0, stream,
                     counts, offsets, cursors, n_tiles, tile_e, tile_s, tile_r);
  hipLaunchKernelGGL(scatter_kernel, dim3(T_TOK / 256), dim3(256), 0, stream,
                     topi, topw, offsets, cursors, ptok, pw);
  hipLaunchKernelGGL(transpose_convert, dim3(DF / 64, DM / 128, NE), dim3(256), 0, stream,
                     w1, wt, DM, DF);                       // w1t into region A
  hipLaunchKernelGGL(gemm1_kernel, dim3(MAX_TILES * (DF / BN)), dim3(256), 0, stream,
                     xb, wt, h, n_tiles, tile_e, tile_s, tile_r, ptok);
  hipLaunchKernelGGL(transpose_convert, dim3(DM / 64, DF / 128, NE), dim3(256), 0, stream,
                     w2, wt, DF, DM);                       // w2t reuses region A
  hipLaunchKernelGGL(gemm2_kernel, dim3(MAX_TILES * (DM / BN)), dim3(256), 0, stream,
                     h, wt, out, n_tiles, tile_e, tile_s, tile_r, ptok, pw);
}

// Round 13
// 384.079 us; speedup vs baseline: 1.1915x; 1.0990x over previous
//
#include <hip/hip_runtime.h>
#include <hip/hip_bf16.h>
#include <stdint.h>

// MoE: T=4096 tokens, D_MODEL=1024, D_FF=4096, E=8, top-2.
// R13: r12 GEMM cores + L2-aware supertile work ordering within balanced
//      XCD chunks; merged route kernel; single transpose dispatch (own w2t).

#define T_TOK 4096
#define DM 1024
#define DF 4096
#define NE 8
#define BM 128              // M tile (pair rows)
#define BN 128              // N tile
#define BK 64               // K step
#define MAX_TILES 72        // sum ceil(c_e/128) <= 64 + 8
#define PAIR_CAP 9216       // MAX_TILES * 128

typedef __bf16 bf16x8 __attribute__((ext_vector_type(8)));
typedef float f32x4 __attribute__((ext_vector_type(4)));
typedef unsigned short ushort_t;

__device__ __forceinline__ ushort_t f2bf(float f) {
  uint32_t u = __float_as_uint(f);
  u += 0x7FFFu + ((u >> 16) & 1u);   // RNE
  return (ushort_t)(u >> 16);
}

// ---- workspace layout (bytes) ----
#define W1T_OFF 0ull                 // [E][DF][DM] bf16 = 64MiB
#define W2T_OFF 67108864ull          // [E][DM][DF] bf16 = 64MiB
#define XB_OFF  134217728ull         // [T][DM] bf16 = 8MiB
#define H_OFF   142606336ull         // [PAIR_CAP][DF] bf16 = 72MiB
#define RT_OFF  218103808ull         // routing block (ends ~208.1MiB.. wait RT at 208MiB)
#define RO_COUNTS   0
#define RO_NTILES   96
#define RO_TILE_E   128              // 288B
#define RO_TILE_S   448              // 288B
#define RO_TILE_R   768              // 288B
#define RO_PTOK     1088             // 36864B
#define RO_PW       37952            // 36864B
#define RO_TOPI     74816            // 32768B
#define RO_TOPW     107584           // 32768B
#define RT_BYTES    140352ull
#define WS_NEEDED   (RT_OFF + RT_BYTES)

// Runtime-balanced XCD-chunked mapping (XCD of block b = b%8).
__device__ __forceinline__ int xcd_work(int b, int live) {
  int k = b & 7, j = b >> 3;
  int q = live >> 3, r = live & 7;
  int cnt = q + (k < r ? 1 : 0);
  if (j >= cnt) return -1;
  int start = k * q + (k < r ? k : r);
  return start + j;
}

// ------------------------------------------------------------------
// 1. Gating (+ fused x fp32 -> bf16), float4-vectorized
// ------------------------------------------------------------------
__global__ void gate_kernel(const float* __restrict__ x, const float* __restrict__ gw,
                            int* __restrict__ counts, int* __restrict__ topi,
                            float* __restrict__ topw, ushort_t* __restrict__ xb) {
  int wave = threadIdx.x >> 6;
  int lane = threadIdx.x & 63;
  int t = blockIdx.x * 4 + wave;
  const float* xr = x + (size_t)t * DM;
  ushort_t* xbr = xb + (size_t)t * DM;
  float acc[NE];
#pragma unroll
  for (int e = 0; e < NE; ++e) acc[e] = 0.f;
#pragma unroll
  for (int it = 0; it < DM / 256; ++it) {
    int d0 = (it * 64 + lane) * 4;
    float4 v = *(const float4*)&xr[d0];
    ushort4 o = { f2bf(v.x), f2bf(v.y), f2bf(v.z), f2bf(v.w) };
    *(ushort4*)&xbr[d0] = o;
    const float* g0 = gw + (size_t)d0 * NE;
#pragma unroll
    for (int e = 0; e < NE; ++e)
      acc[e] += v.x * g0[e] + v.y * g0[NE + e] + v.z * g0[2 * NE + e] + v.w * g0[3 * NE + e];
  }
#pragma unroll
  for (int off = 32; off > 0; off >>= 1) {
#pragma unroll
    for (int e = 0; e < NE; ++e) acc[e] += __shfl_xor(acc[e], off, 64);
  }
  if (lane == 0) {
    int i0 = 0; float v0 = acc[0];
#pragma unroll
    for (int e = 1; e < NE; ++e) if (acc[e] > v0) { v0 = acc[e]; i0 = e; }
    int i1 = -1; float v1 = -1e30f;
#pragma unroll
    for (int e = 0; e < NE; ++e) if (e != i0 && acc[e] > v1) { v1 = acc[e]; i1 = e; }
    float e1 = expf(v1 - v0);
    float w0 = 1.f / (1.f + e1);
    float w1 = e1 / (1.f + e1);
    topi[t * 2] = i0; topi[t * 2 + 1] = i1;
    topw[t * 2] = w0; topw[t * 2 + 1] = w1;
    atomicAdd(&counts[i0], 1);
    atomicAdd(&counts[i1], 1);
  }
}

// ------------------------------------------------------------------
// 2. Route: scan (thread 0) + parallel scatter, one block, LDS cursors
// ------------------------------------------------------------------
__global__ void route_kernel(const int* __restrict__ counts,
                             const int* __restrict__ topi, const float* __restrict__ topw,
                             int* __restrict__ n_tiles, int* __restrict__ tile_e,
                             int* __restrict__ tile_s, int* __restrict__ tile_r,
                             int* __restrict__ ptok, float* __restrict__ pw) {
  __shared__ int loff[NE];
  __shared__ int lcur[NE];
  if (threadIdx.x == 0) {
    int off = 0, nt = 0;
    for (int e = 0; e < NE; ++e) {
      loff[e] = off;
      lcur[e] = 0;
      int c = counts[e];
      for (int m0 = 0; m0 < c; m0 += BM) {
        tile_e[nt] = e;
        tile_s[nt] = off + m0;
        tile_r[nt] = (c - m0 < BM) ? (c - m0) : BM;
        ++nt;
      }
      off += ((c + BM - 1) / BM) * BM;
    }
    *n_tiles = nt;
  }
  __syncthreads();
  for (int t = threadIdx.x; t < T_TOK; t += 256) {
#pragma unroll
    for (int k = 0; k < 2; ++k) {
      int e = topi[t * 2 + k];
      int pos = atomicAdd(&lcur[e], 1);
      int p = loff[e] + pos;
      ptok[p] = t;
      pw[p] = topw[t * 2 + k];
    }
  }
}

// ------------------------------------------------------------------
// 3. Both weights: fp32 [E][R][C] -> bf16 transposed [E][C][R], one dispatch
//    b < 4096: w1 (R=DM, C=DF);  b >= 4096: w2 (R=DF, C=DM)
// ------------------------------------------------------------------
__global__ void transpose_all(const float* __restrict__ w1, const float* __restrict__ w2,
                              ushort_t* __restrict__ w1t, ushort_t* __restrict__ w2t) {
  __shared__ ushort_t tile[64][136];
  int b = blockIdx.x;
  const float* src; ushort_t* dst; int R, C, bx, by, e;
  if (b < 4096) {
    e = b >> 9; int t2 = b & 511;
    bx = t2 & 63; by = t2 >> 6;          // 64 x 8
    src = w1; dst = w1t; R = DM; C = DF;
  } else {
    b -= 4096;
    e = b >> 9; int t2 = b & 511;
    bx = t2 & 15; by = t2 >> 4;          // 16 x 32
    src = w2; dst = w2t; R = DF; C = DM;
  }
  src += (size_t)e * R * C;
  dst += (size_t)e * R * C;
  int c0 = bx * 64, r0 = by * 128;
  int tr = threadIdx.x >> 4;
  int tc = (threadIdx.x & 15) << 2;
#pragma unroll
  for (int i = 0; i < 8; ++i) {
    int r = i * 16 + tr;
    float4 v = *(const float4*)&src[(size_t)(r0 + r) * C + c0 + tc];
    tile[tc + 0][r] = f2bf(v.x);
    tile[tc + 1][r] = f2bf(v.y);
    tile[tc + 2][r] = f2bf(v.z);
    tile[tc + 3][r] = f2bf(v.w);
  }
  __syncthreads();
  int cr = threadIdx.x >> 5;
  int rg = (threadIdx.x & 31) << 2;
#pragma unroll
  for (int j = 0; j < 8; ++j) {
    int c = j * 8 + cr;
    ushort4 o = { tile[c][rg], tile[c][rg + 1], tile[c][rg + 2], tile[c][rg + 3] };
    *(ushort4*)&dst[(size_t)(c0 + c) * R + r0 + rg] = o;
  }
}

// ==================================================================
// m97-replica 128x128xBK64 grouped-GEMM core (unchanged from r12).
// ==================================================================

#define GLD(srcp, dstp)                                                        \
  __builtin_amdgcn_global_load_lds(                                            \
      (const __attribute__((address_space(1))) void*)(srcp),                   \
      (__attribute__((address_space(3))) void*)(dstp), 16, 0, 0)

__device__ __forceinline__ void gemm_core(
    ushort_t* As, ushort_t* Bs,
    const ushort_t* const (&a_sp)[4], const ushort_t* const (&b_sp)[4],
    int NT, int wid, int lane, f32x4 (&acc)[4][4]) {
  int fr = lane & 15, ch = lane >> 4, sw = lane & 7;
  int k0s = (ch ^ sw) * 8;
  int k1s = ((ch + 4) ^ sw) * 8;
  int m_off = (wid >> 1) * 64, n_off = (wid & 1) * 64;
  int abase = (m_off + fr) * 64;
  int bbase = (n_off + fr) * 64;

  for (int t = 0; t < NT; ++t) {
    int k0 = t * BK;
#pragma unroll
    for (int j = 0; j < 4; ++j) {
      GLD(a_sp[j] + k0, As + (wid * 4 + j) * 512);
      GLD(b_sp[j] + k0, Bs + (wid * 4 + j) * 512);
    }
    asm volatile("s_waitcnt vmcnt(0)" ::: "memory");
    __syncthreads();

#pragma unroll
    for (int kx = 0; kx < 2; ++kx) {
      int ks = kx ? k1s : k0s;
      bf16x8 af[4], bf[4];
#pragma unroll
      for (int mi = 0; mi < 4; ++mi) af[mi] = *(const bf16x8*)&As[abase + mi * 1024 + ks];
#pragma unroll
      for (int ni = 0; ni < 4; ++ni) bf[ni] = *(const bf16x8*)&Bs[bbase + ni * 1024 + ks];
#pragma unroll
      for (int mi = 0; mi < 4; ++mi)
#pragma unroll
        for (int ni = 0; ni < 4; ++ni)
          acc[mi][ni] = __builtin_amdgcn_mfma_f32_16x16x32_bf16(af[mi], bf[ni], acc[mi][ni], 0, 0, 0);
    }
    __syncthreads();
  }
}

// ------------------------------------------------------------------
// 5. GEMM1: h[p][:] = relu(x[tok(p)] @ W1_e)
//    Supertile order: groups of 4 tiles x 8 n0 (L2 set ~3MB), ng inner
//    of tg so the A set persists across n0-groups.
// ------------------------------------------------------------------
__global__ __launch_bounds__(256, 4) void gemm1_kernel(
    const ushort_t* __restrict__ xb, const ushort_t* __restrict__ w1t,
    ushort_t* __restrict__ h,
    const int* __restrict__ n_tiles, const int* __restrict__ tile_e,
    const int* __restrict__ tile_s, const int* __restrict__ tile_r,
    const int* __restrict__ ptok) {
  int nt = *n_tiles;
  int ntp = (nt + 3) & ~3;
  int w = xcd_work(blockIdx.x, ntp * 32);
  if (w < 0) return;
  int g = w >> 5, r = w & 31;          // 32 works per group
  int tg = g >> 2, ng = g & 3;         // 4 n0-groups per tile-group
  int tile = tg * 4 + (r & 3);
  if (tile >= nt) return;
  int n0 = (ng * 8 + (r >> 2)) * BN;
  int e = tile_e[tile], p0 = tile_s[tile], rows = tile_r[tile];

  __shared__ ushort_t As[BM * BK];
  __shared__ ushort_t Bs[BN * BK];
  int tid = threadIdx.x, wid = tid >> 6, lane = tid & 63;
  int lr = lane >> 3;
  int swc = (lane & 7) ^ (lr & 7);

  const ushort_t* a_sp[4];
  const ushort_t* b_sp[4];
#pragma unroll
  for (int j = 0; j < 4; ++j) {
    int rr = wid * 32 + j * 8 + lr;
    int tok = (rr < rows) ? ptok[p0 + rr] : 0;
    a_sp[j] = xb + (size_t)tok * DM + swc * 8;
    b_sp[j] = w1t + ((size_t)e * DF + n0 + rr) * DM + swc * 8;
  }

  f32x4 acc[4][4] = {};
  gemm_core(As, Bs, a_sp, b_sp, DM / BK, wid, lane, acc);

  int m_off = (wid >> 1) * 64, n_off = (wid & 1) * 64;
  int col = lane & 15, rq = (lane >> 4) * 4;
#pragma unroll
  for (int mi = 0; mi < 4; ++mi)
#pragma unroll
    for (int rr = 0; rr < 4; ++rr) {
      int m = m_off + mi * 16 + rq + rr;
      bool valid = m < rows;
      size_t rowoff = (size_t)(p0 + m) * DF + n0 + n_off;
#pragma unroll
      for (int ni = 0; ni < 4; ++ni) {
        float v = acc[mi][ni][rr];
        v = valid ? (v > 0.f ? v : 0.f) : 0.f;
        h[rowoff + ni * 16 + col] = f2bf(v);
      }
    }
}

// ------------------------------------------------------------------
// 6. GEMM2: out[tok(p)] += pw[p] * (h[p] @ W2_e)   (atomic epilogue)
//    Supertile order: groups of 2 tiles x 2 n0 (~4MB L2 set).
// ------------------------------------------------------------------
__global__ __launch_bounds__(256, 4) void gemm2_kernel(
    const ushort_t* __restrict__ h, const ushort_t* __restrict__ w2t,
    float* __restrict__ out,
    const int* __restrict__ n_tiles, const int* __restrict__ tile_e,
    const int* __restrict__ tile_s, const int* __restrict__ tile_r,
    const int* __restrict__ ptok, const float* __restrict__ pw) {
  int nt = *n_tiles;
  int ntp = (nt + 1) & ~1;
  int w = xcd_work(blockIdx.x, ntp * 8);
  if (w < 0) return;
  int g = w >> 2, r = w & 3;           // 4 works per group
  int tg = g >> 2, ng = g & 3;         // 4 n0-groups per tile-group
  int tile = tg * 2 + (r & 1);
  if (tile >= nt) return;
  int n0 = (ng * 2 + (r >> 1)) * BN;
  int e = tile_e[tile], p0 = tile_s[tile], rows = tile_r[tile];

  __shared__ ushort_t As[BM * BK];
  __shared__ ushort_t Bs[BN * BK];
  int tid = threadIdx.x, wid = tid >> 6, lane = tid & 63;
  int lr = lane >> 3;
  int swc = (lane & 7) ^ (lr & 7);

  const ushort_t* a_sp[4];
  const ushort_t* b_sp[4];
#pragma unroll
  for (int j = 0; j < 4; ++j) {
    int rr = wid * 32 + j * 8 + lr;
    a_sp[j] = h + (size_t)(p0 + rr) * DF + swc * 8;
    b_sp[j] = w2t + ((size_t)e * DM + n0 + rr) * DF + swc * 8;
  }

  f32x4 acc[4][4] = {};
  gemm_core(As, Bs, a_sp, b_sp, DF / BK, wid, lane, acc);

  int m_off = (wid >> 1) * 64, n_off = (wid & 1) * 64;
  int col = lane & 15, rq = (lane >> 4) * 4;
#pragma unroll
  for (int mi = 0; mi < 4; ++mi)
#pragma unroll
    for (int rr = 0; rr < 4; ++rr) {
      int m = m_off + mi * 16 + rq + rr;
      if (m < rows) {
        int p = p0 + m;
        int tok = ptok[p];
        float wgt = pw[p];
        size_t o = (size_t)tok * DM + n0 + n_off;
#pragma unroll
        for (int ni = 0; ni < 4; ++ni)
          atomicAdd(&out[o + ni * 16 + col], wgt * acc[mi][ni][rr]);
      }
    }
}

// ------------------------------------------------------------------
extern "C" void kernel_launch(void* const* d_in, const int* in_sizes, int n_in,
                              void* d_out, int out_size, void* d_ws, size_t ws_size,
                              hipStream_t stream) {
  const float* x  = (const float*)d_in[0];   // [2,2048,1024]
  const float* gw = (const float*)d_in[1];   // [1024,8]
  const float* w1 = (const float*)d_in[2];   // [8,1024,4096]
  const float* w2 = (const float*)d_in[3];   // [8,4096,1024]
  float* out = (float*)d_out;                // [4096,1024]
  char* ws = (char*)d_ws;
  if (ws_size < WS_NEEDED) return;

  ushort_t* w1t = (ushort_t*)(ws + W1T_OFF);
  ushort_t* w2t = (ushort_t*)(ws + W2T_OFF);
  ushort_t* xb  = (ushort_t*)(ws + XB_OFF);
  ushort_t* h   = (ushort_t*)(ws + H_OFF);
  char* rt = ws + RT_OFF;
  int*   counts  = (int*)(rt + RO_COUNTS);
  int*   n_tiles = (int*)(rt + RO_NTILES);
  int*   tile_e  = (int*)(rt + RO_TILE_E);
  int*   tile_s  = (int*)(rt + RO_TILE_S);
  int*   tile_r  = (int*)(rt + RO_TILE_R);
  int*   ptok    = (int*)(rt + RO_PTOK);
  float* pw      = (float*)(rt + RO_PW);
  int*   topi    = (int*)(rt + RO_TOPI);
  float* topw    = (float*)(rt + RO_TOPW);

  hipMemsetAsync(rt, 0, 128, stream);
  hipMemsetAsync(out, 0, (size_t)T_TOK * DM * sizeof(float), stream);

  hipLaunchKernelGGL(gate_kernel, dim3(T_TOK / 4), dim3(256), 0, stream,
                     x, gw, counts, topi, topw, xb);
  hipLaunchKernelGGL(route_kernel, dim3(1), dim3(256), 0, stream,
                     counts, topi, topw, n_tiles, tile_e, tile_s, tile_r, ptok, pw);
  hipLaunchKernelGGL(transpose_all, dim3(8192), dim3(256), 0, stream,
                     w1, w2, w1t, w2t);
  hipLaunchKernelGGL(gemm1_kernel, dim3(MAX_TILES * 32), dim3(256), 0, stream,
                     xb, w1t, h, n_tiles, tile_e, tile_s, tile_r, ptok);
  hipLaunchKernelGGL(gemm2_kernel, dim3(MAX_TILES * 8), dim3(256), 0, stream,
                     h, w2t, out, n_tiles, tile_e, tile_s, tile_r, ptok, pw);
}

// Round 14
// 367.588 us; speedup vs baseline: 1.2449x; 1.0449x over previous
//
#include <hip/hip_runtime.h>
#include <hip/hip_bf16.h>
#include <stdint.h>

// MoE: T=4096 tokens, D_MODEL=1024, D_FF=4096, E=8, top-2.
// R14: r13 + block-specialization fusion: {gate ∥ w1-transpose} and
//      {gemm1 ∥ w2-transpose} share dispatches to hide the serial
//      transpose phases. GEMM cores/supertile order unchanged.

#define T_TOK 4096
#define DM 1024
#define DF 4096
#define NE 8
#define BM 128              // M tile (pair rows)
#define BN 128              // N tile
#define BK 64               // K step
#define MAX_TILES 72        // sum ceil(c_e/128) <= 64 + 8
#define PAIR_CAP 9216       // MAX_TILES * 128
#define G1_GRID (MAX_TILES * 32)     // 2304 gemm1 work slots

typedef __bf16 bf16x8 __attribute__((ext_vector_type(8)));
typedef float f32x4 __attribute__((ext_vector_type(4)));
typedef unsigned short ushort_t;

__device__ __forceinline__ ushort_t f2bf(float f) {
  uint32_t u = __float_as_uint(f);
  u += 0x7FFFu + ((u >> 16) & 1u);   // RNE
  return (ushort_t)(u >> 16);
}

// ---- workspace layout (bytes) ----
#define W1T_OFF 0ull                 // [E][DF][DM] bf16 = 64MiB
#define W2T_OFF 67108864ull          // [E][DM][DF] bf16 = 64MiB
#define XB_OFF  134217728ull         // [T][DM] bf16 = 8MiB
#define H_OFF   142606336ull         // [PAIR_CAP][DF] bf16 = 72MiB
#define RT_OFF  218103808ull         // routing block
#define RO_COUNTS   0
#define RO_NTILES   96
#define RO_TILE_E   128              // 288B
#define RO_TILE_S   448              // 288B
#define RO_TILE_R   768              // 288B
#define RO_PTOK     1088             // 36864B
#define RO_PW       37952            // 36864B
#define RO_TOPI     74816            // 32768B
#define RO_TOPW     107584           // 32768B
#define RT_BYTES    140352ull
#define WS_NEEDED   (RT_OFF + RT_BYTES)

// Runtime-balanced XCD-chunked mapping (XCD of block b = b%8).
__device__ __forceinline__ int xcd_work(int b, int live) {
  int k = b & 7, j = b >> 3;
  int q = live >> 3, r = live & 7;
  int cnt = q + (k < r ? 1 : 0);
  if (j >= cnt) return -1;
  int start = k * q + (k < r ? k : r);
  return start + j;
}

// ------------------------------------------------------------------
// shared transpose body: one 128r x 64c fp32 tile -> bf16 [C][R]
// sh must hold >= 8704 ushorts (used as tile[64][136], [c][r] indexed)
// ------------------------------------------------------------------
__device__ __forceinline__ void transpose_tile(
    ushort_t* sh, const float* __restrict__ src, ushort_t* __restrict__ dst,
    int R, int C, int bx, int by, int e) {
  src += (size_t)e * R * C;
  dst += (size_t)e * R * C;
  int c0 = bx * 64, r0 = by * 128;
  int tr = threadIdx.x >> 4;          // 0..15
  int tc = (threadIdx.x & 15) << 2;   // 0..60
#pragma unroll
  for (int i = 0; i < 8; ++i) {
    int r = i * 16 + tr;
    float4 v = *(const float4*)&src[(size_t)(r0 + r) * C + c0 + tc];
    sh[(tc + 0) * 136 + r] = f2bf(v.x);
    sh[(tc + 1) * 136 + r] = f2bf(v.y);
    sh[(tc + 2) * 136 + r] = f2bf(v.z);
    sh[(tc + 3) * 136 + r] = f2bf(v.w);
  }
  __syncthreads();
  int cr = threadIdx.x >> 5;          // 0..7
  int rg = (threadIdx.x & 31) << 2;   // 0..124
#pragma unroll
  for (int j = 0; j < 8; ++j) {
    int c = j * 8 + cr;
    ushort4 o = { sh[c * 136 + rg], sh[c * 136 + rg + 1],
                  sh[c * 136 + rg + 2], sh[c * 136 + rg + 3] };
    *(ushort4*)&dst[(size_t)(c0 + c) * R + r0 + rg] = o;
  }
}

// ------------------------------------------------------------------
// 1. Fused: gate (+x->bf16) blocks [0,1024) ∥ w1-transpose blocks [1024,5120)
// ------------------------------------------------------------------
__global__ __launch_bounds__(256) void gate_w1t_kernel(
    const float* __restrict__ x, const float* __restrict__ gw,
    int* __restrict__ counts, int* __restrict__ topi,
    float* __restrict__ topw, ushort_t* __restrict__ xb,
    const float* __restrict__ w1, ushort_t* __restrict__ w1t) {
  __shared__ ushort_t sh[8704];
  int b = blockIdx.x;
  if (b >= 1024) {
    int t = b - 1024;                 // 4096 blocks: e(8) x by(8) x bx(64)
    int e = t >> 9, t2 = t & 511;
    transpose_tile(sh, w1, w1t, DM, DF, t2 & 63, t2 >> 6, e);
    return;
  }
  int wave = threadIdx.x >> 6;
  int lane = threadIdx.x & 63;
  int t = b * 4 + wave;
  const float* xr = x + (size_t)t * DM;
  ushort_t* xbr = xb + (size_t)t * DM;
  float acc[NE];
#pragma unroll
  for (int e = 0; e < NE; ++e) acc[e] = 0.f;
#pragma unroll
  for (int it = 0; it < DM / 256; ++it) {
    int d0 = (it * 64 + lane) * 4;
    float4 v = *(const float4*)&xr[d0];
    ushort4 o = { f2bf(v.x), f2bf(v.y), f2bf(v.z), f2bf(v.w) };
    *(ushort4*)&xbr[d0] = o;
    const float* g0 = gw + (size_t)d0 * NE;
#pragma unroll
    for (int e = 0; e < NE; ++e)
      acc[e] += v.x * g0[e] + v.y * g0[NE + e] + v.z * g0[2 * NE + e] + v.w * g0[3 * NE + e];
  }
#pragma unroll
  for (int off = 32; off > 0; off >>= 1) {
#pragma unroll
    for (int e = 0; e < NE; ++e) acc[e] += __shfl_xor(acc[e], off, 64);
  }
  if (lane == 0) {
    int i0 = 0; float v0 = acc[0];
#pragma unroll
    for (int e = 1; e < NE; ++e) if (acc[e] > v0) { v0 = acc[e]; i0 = e; }
    int i1 = -1; float v1 = -1e30f;
#pragma unroll
    for (int e = 0; e < NE; ++e) if (e != i0 && acc[e] > v1) { v1 = acc[e]; i1 = e; }
    float e1 = expf(v1 - v0);
    float w0 = 1.f / (1.f + e1);
    float w1s = e1 / (1.f + e1);
    topi[t * 2] = i0; topi[t * 2 + 1] = i1;
    topw[t * 2] = w0; topw[t * 2 + 1] = w1s;
    atomicAdd(&counts[i0], 1);
    atomicAdd(&counts[i1], 1);
  }
}

// ------------------------------------------------------------------
// 2. Route: scan (thread 0) + parallel scatter, one block, LDS cursors
// ------------------------------------------------------------------
__global__ void route_kernel(const int* __restrict__ counts,
                             const int* __restrict__ topi, const float* __restrict__ topw,
                             int* __restrict__ n_tiles, int* __restrict__ tile_e,
                             int* __restrict__ tile_s, int* __restrict__ tile_r,
                             int* __restrict__ ptok, float* __restrict__ pw) {
  __shared__ int loff[NE];
  __shared__ int lcur[NE];
  if (threadIdx.x == 0) {
    int off = 0, nt = 0;
    for (int e = 0; e < NE; ++e) {
      loff[e] = off;
      lcur[e] = 0;
      int c = counts[e];
      for (int m0 = 0; m0 < c; m0 += BM) {
        tile_e[nt] = e;
        tile_s[nt] = off + m0;
        tile_r[nt] = (c - m0 < BM) ? (c - m0) : BM;
        ++nt;
      }
      off += ((c + BM - 1) / BM) * BM;
    }
    *n_tiles = nt;
  }
  __syncthreads();
  for (int t = threadIdx.x; t < T_TOK; t += 256) {
#pragma unroll
    for (int k = 0; k < 2; ++k) {
      int e = topi[t * 2 + k];
      int pos = atomicAdd(&lcur[e], 1);
      int p = loff[e] + pos;
      ptok[p] = t;
      pw[p] = topw[t * 2 + k];
    }
  }
}

// ==================================================================
// m97-replica 128x128xBK64 grouped-GEMM core (unchanged).
// ==================================================================

#define GLD(srcp, dstp)                                                        \
  __builtin_amdgcn_global_load_lds(                                            \
      (const __attribute__((address_space(1))) void*)(srcp),                   \
      (__attribute__((address_space(3))) void*)(dstp), 16, 0, 0)

__device__ __forceinline__ void gemm_core(
    ushort_t* As, ushort_t* Bs,
    const ushort_t* const (&a_sp)[4], const ushort_t* const (&b_sp)[4],
    int NT, int wid, int lane, f32x4 (&acc)[4][4]) {
  int fr = lane & 15, ch = lane >> 4, sw = lane & 7;
  int k0s = (ch ^ sw) * 8;
  int k1s = ((ch + 4) ^ sw) * 8;
  int m_off = (wid >> 1) * 64, n_off = (wid & 1) * 64;
  int abase = (m_off + fr) * 64;
  int bbase = (n_off + fr) * 64;

  for (int t = 0; t < NT; ++t) {
    int k0 = t * BK;
#pragma unroll
    for (int j = 0; j < 4; ++j) {
      GLD(a_sp[j] + k0, As + (wid * 4 + j) * 512);
      GLD(b_sp[j] + k0, Bs + (wid * 4 + j) * 512);
    }
    asm volatile("s_waitcnt vmcnt(0)" ::: "memory");
    __syncthreads();

#pragma unroll
    for (int kx = 0; kx < 2; ++kx) {
      int ks = kx ? k1s : k0s;
      bf16x8 af[4], bf[4];
#pragma unroll
      for (int mi = 0; mi < 4; ++mi) af[mi] = *(const bf16x8*)&As[abase + mi * 1024 + ks];
#pragma unroll
      for (int ni = 0; ni < 4; ++ni) bf[ni] = *(const bf16x8*)&Bs[bbase + ni * 1024 + ks];
#pragma unroll
      for (int mi = 0; mi < 4; ++mi)
#pragma unroll
        for (int ni = 0; ni < 4; ++ni)
          acc[mi][ni] = __builtin_amdgcn_mfma_f32_16x16x32_bf16(af[mi], bf[ni], acc[mi][ni], 0, 0, 0);
    }
    __syncthreads();
  }
}

// ------------------------------------------------------------------
// 3. Fused: gemm1 blocks [0,2304) ∥ w2-transpose blocks [2304,6400).
//    gemm1: h[p][:] = relu(x[tok(p)] @ W1_e), supertile 4 tiles x 8 n0.
// ------------------------------------------------------------------
__global__ __launch_bounds__(256, 4) void gemm1_w2t_kernel(
    const ushort_t* __restrict__ xb, const ushort_t* __restrict__ w1t,
    ushort_t* __restrict__ h,
    const int* __restrict__ n_tiles, const int* __restrict__ tile_e,
    const int* __restrict__ tile_s, const int* __restrict__ tile_r,
    const int* __restrict__ ptok,
    const float* __restrict__ w2, ushort_t* __restrict__ w2t) {
  __shared__ ushort_t sh[BM * BK + BN * BK];   // 32 KiB; transpose uses 8704
  int b = blockIdx.x;
  if (b >= G1_GRID) {
    int t = b - G1_GRID;              // 4096 blocks: e(8) x by(32) x bx(16)
    int e = t >> 9, t2 = t & 511;
    transpose_tile(sh, w2, w2t, DF, DM, t2 & 15, t2 >> 4, e);
    return;
  }
  int nt = *n_tiles;
  int ntp = (nt + 3) & ~3;
  int w = xcd_work(b, ntp * 32);
  if (w < 0) return;
  int g = w >> 5, r = w & 31;
  int tg = g >> 2, ng = g & 3;
  int tile = tg * 4 + (r & 3);
  if (tile >= nt) return;
  int n0 = (ng * 8 + (r >> 2)) * BN;
  int e = tile_e[tile], p0 = tile_s[tile], rows = tile_r[tile];

  ushort_t* As = sh;
  ushort_t* Bs = sh + BM * BK;
  int tid = threadIdx.x, wid = tid >> 6, lane = tid & 63;
  int lr = lane >> 3;
  int swc = (lane & 7) ^ (lr & 7);

  const ushort_t* a_sp[4];
  const ushort_t* b_sp[4];
#pragma unroll
  for (int j = 0; j < 4; ++j) {
    int rr = wid * 32 + j * 8 + lr;
    int tok = (rr < rows) ? ptok[p0 + rr] : 0;
    a_sp[j] = xb + (size_t)tok * DM + swc * 8;
    b_sp[j] = w1t + ((size_t)e * DF + n0 + rr) * DM + swc * 8;
  }

  f32x4 acc[4][4] = {};
  gemm_core(As, Bs, a_sp, b_sp, DM / BK, wid, lane, acc);

  int m_off = (wid >> 1) * 64, n_off = (wid & 1) * 64;
  int col = lane & 15, rq = (lane >> 4) * 4;
#pragma unroll
  for (int mi = 0; mi < 4; ++mi)
#pragma unroll
    for (int rr = 0; rr < 4; ++rr) {
      int m = m_off + mi * 16 + rq + rr;
      bool valid = m < rows;
      size_t rowoff = (size_t)(p0 + m) * DF + n0 + n_off;
#pragma unroll
      for (int ni = 0; ni < 4; ++ni) {
        float v = acc[mi][ni][rr];
        v = valid ? (v > 0.f ? v : 0.f) : 0.f;
        h[rowoff + ni * 16 + col] = f2bf(v);
      }
    }
}

// ------------------------------------------------------------------
// 4. GEMM2: out[tok(p)] += pw[p] * (h[p] @ W2_e)   (atomic epilogue,
//    2 commutative adds/element -> deterministic). Supertile 2x2.
// ------------------------------------------------------------------
__global__ __launch_bounds__(256, 4) void gemm2_kernel(
    const ushort_t* __restrict__ h, const ushort_t* __restrict__ w2t,
    float* __restrict__ out,
    const int* __restrict__ n_tiles, const int* __restrict__ tile_e,
    const int* __restrict__ tile_s, const int* __restrict__ tile_r,
    const int* __restrict__ ptok, const float* __restrict__ pw) {
  int nt = *n_tiles;
  int ntp = (nt + 1) & ~1;
  int w = xcd_work(blockIdx.x, ntp * 8);
  if (w < 0) return;
  int g = w >> 2, r = w & 3;
  int tg = g >> 2, ng = g & 3;
  int tile = tg * 2 + (r & 1);
  if (tile >= nt) return;
  int n0 = (ng * 2 + (r >> 1)) * BN;
  int e = tile_e[tile], p0 = tile_s[tile], rows = tile_r[tile];

  __shared__ ushort_t As[BM * BK];
  __shared__ ushort_t Bs[BN * BK];
  int tid = threadIdx.x, wid = tid >> 6, lane = tid & 63;
  int lr = lane >> 3;
  int swc = (lane & 7) ^ (lr & 7);

  const ushort_t* a_sp[4];
  const ushort_t* b_sp[4];
#pragma unroll
  for (int j = 0; j < 4; ++j) {
    int rr = wid * 32 + j * 8 + lr;
    a_sp[j] = h + (size_t)(p0 + rr) * DF + swc * 8;
    b_sp[j] = w2t + ((size_t)e * DM + n0 + rr) * DF + swc * 8;
  }

  f32x4 acc[4][4] = {};
  gemm_core(As, Bs, a_sp, b_sp, DF / BK, wid, lane, acc);

  int m_off = (wid >> 1) * 64, n_off = (wid & 1) * 64;
  int col = lane & 15, rq = (lane >> 4) * 4;
#pragma unroll
  for (int mi = 0; mi < 4; ++mi)
#pragma unroll
    for (int rr = 0; rr < 4; ++rr) {
      int m = m_off + mi * 16 + rq + rr;
      if (m < rows) {
        int p = p0 + m;
        int tok = ptok[p];
        float wgt = pw[p];
        size_t o = (size_t)tok * DM + n0 + n_off;
#pragma unroll
        for (int ni = 0; ni < 4; ++ni)
          atomicAdd(&out[o + ni * 16 + col], wgt * acc[mi][ni][rr]);
      }
    }
}

// ------------------------------------------------------------------
extern "C" void kernel_launch(void* const* d_in, const int* in_sizes, int n_in,
                              void* d_out, int out_size, void* d_ws, size_t ws_size,
                              hipStream_t stream) {
  const float* x  = (const float*)d_in[0];   // [2,2048,1024]
  const float* gw = (const float*)d_in[1];   // [1024,8]
  const float* w1 = (const float*)d_in[2];   // [8,1024,4096]
  const float* w2 = (const float*)d_in[3];   // [8,4096,1024]
  float* out = (float*)d_out;                // [4096,1024]
  char* ws = (char*)d_ws;
  if (ws_size < WS_NEEDED) return;

  ushort_t* w1t = (ushort_t*)(ws + W1T_OFF);
  ushort_t* w2t = (ushort_t*)(ws + W2T_OFF);
  ushort_t* xb  = (ushort_t*)(ws + XB_OFF);
  ushort_t* h   = (ushort_t*)(ws + H_OFF);
  char* rt = ws + RT_OFF;
  int*   counts  = (int*)(rt + RO_COUNTS);
  int*   n_tiles = (int*)(rt + RO_NTILES);
  int*   tile_e  = (int*)(rt + RO_TILE_E);
  int*   tile_s  = (int*)(rt + RO_TILE_S);
  int*   tile_r  = (int*)(rt + RO_TILE_R);
  int*   ptok    = (int*)(rt + RO_PTOK);
  float* pw      = (float*)(rt + RO_PW);
  int*   topi    = (int*)(rt + RO_TOPI);
  float* topw    = (float*)(rt + RO_TOPW);

  hipMemsetAsync(rt, 0, 128, stream);
  hipMemsetAsync(out, 0, (size_t)T_TOK * DM * sizeof(float), stream);

  hipLaunchKernelGGL(gate_w1t_kernel, dim3(1024 + 4096), dim3(256), 0, stream,
                     x, gw, counts, topi, topw, xb, w1, w1t);
  hipLaunchKernelGGL(route_kernel, dim3(1), dim3(256), 0, stream,
                     counts, topi, topw, n_tiles, tile_e, tile_s, tile_r, ptok, pw);
  hipLaunchKernelGGL(gemm1_w2t_kernel, dim3(G1_GRID + 4096), dim3(256), 0, stream,
                     xb, w1t, h, n_tiles, tile_e, tile_s, tile_r, ptok, w2, w2t);
  hipLaunchKernelGGL(gemm2_kernel, dim3(MAX_TILES * 8), dim3(256), 0, stream,
                     h, w2t, out, n_tiles, tile_e, tile_s, tile_r, ptok, pw);
}